// Round 10
// baseline (152.746 us; speedup 1.0000x reference)
//
#include <hip/hip_runtime.h>
#include <stdint.h>

// Problem constants (reference: N=2048, M=100000, D=128, K=5)
#define N_Q 2048
#define M_B 100000
#define D_DIM 128
#define KNN 5
#define SLABS_TOTAL 1563            // ceil(M/64)
#define M_PAD (SLABS_TOTAL * 64)    // 100032
#define CHUNKS 64                   // R18: m201 geometry -> grid 256 = 1 blk/CU
#define SPC 25                      // slabs per chunk; chunk 62: 13; 63 empty
#define CLS 16                      // col classes per chunk: col mod 16
#define FTOT (CHUNKS * CLS)         // 1024 rsm entries per row (phantoms = NEGF)
#define ROWBLOCKS 4
#define TROWS 512                   // 8 waves x 64 rows/wave
#define BIGF 3.0e38f
#define NEGF -3.0e38f

// Accuracy (R9-R18, refines validated R6/R8 scheme): output = top-5 of per-
// (chunk x col-mod-16 class) bf16 acc maxima -- 1008 real candidate classes
// per row (63 non-empty chunks x 16; same set as R12/R16-style). acc
// excludes the row-constant -x^2/2 (cannot change per-row argmax); k_scan
// reconstructs d2 = x2 - 2*acc with fp32 x2. fmax is order-insensitive ->
// same numerics as R16/R17 (absmax expected unchanged at 0.125).

typedef __attribute__((ext_vector_type(8))) short short8;      // MFMA A/B frag (8 bf16)
typedef __attribute__((ext_vector_type(4))) unsigned short ushort4v;
typedef __attribute__((ext_vector_type(8))) unsigned short ushort8v;
typedef __attribute__((ext_vector_type(4))) float f32x4;       // 16x16 MFMA C/D frag

static __device__ __forceinline__ unsigned short f2bf(float f) {
  unsigned int u = __builtin_bit_cast(unsigned int, f);
  u = (u + 0x7FFFu + ((u >> 16) & 1u)) >> 16;   // RNE
  return (unsigned short)u;
}

static __device__ __forceinline__ void gload_lds16(const void* g, void* l) {
  __builtin_amdgcn_global_load_lds((const __attribute__((address_space(1))) unsigned int*)g,
                                   (__attribute__((address_space(3))) unsigned int*)l, 16, 0, 0);
}
static __device__ __forceinline__ void gload_lds4(const void* g, void* l) {
  __builtin_amdgcn_global_load_lds((const __attribute__((address_space(1))) unsigned int*)g,
                                   (__attribute__((address_space(3))) unsigned int*)l, 4, 0, 0);
}

#define DPPADD(v, ctrl)                                                              \
  do {                                                                               \
    int _t = __builtin_amdgcn_update_dpp(0, __builtin_bit_cast(int, (v)), (ctrl),    \
                                         0xf, 0xf, false);                           \
    (v) = (v) + __builtin_bit_cast(float, _t);                                       \
  } while (0)

// ---------------------------------------------------------------------------
// K0: bank fp32 -> bf16 slab-tiled + ny2 = -0.5*|y|^2 (pads NEGF).
// Lane-contiguous flat reads; LDS-staged tile; coalesced 16B/lane writes.
// Tiled layout: slab s, unit u = kc*64 + j holds Y[s*64+j][kc*8 .. kc*8+8).
// ---------------------------------------------------------------------------
__global__ __launch_bounds__(256) void k_prep(const float* __restrict__ Y,
                                              unsigned short* __restrict__ ybf,
                                              float* __restrict__ ny2) {
  const int s = blockIdx.x;
  const int t = threadIdx.x;
  __shared__ __align__(16) unsigned short tile[8192];   // 16 KB bf16 slab
  __shared__ float redy[64 * 33];                       // padded
#pragma unroll
  for (int i = 0; i < 8; ++i) {
    const int u = i * 256 + t;                  // flat float4 index in 32KB slab
    const int rowl = u >> 5;                    // 0..63
    const int q = u & 31;                       // float4 within row
    const int rowg = s * 64 + rowl;
    const int rowc = (rowg < M_B) ? rowg : (M_B - 1);
    const float4 v = ((const float4*)Y)[(size_t)rowc * 32 + q];
    redy[rowl * 33 + q] = v.x * v.x + v.y * v.y + v.z * v.z + v.w * v.w;
    ushort4v o;
    o[0] = f2bf(v.x); o[1] = f2bf(v.y); o[2] = f2bf(v.z); o[3] = f2bf(v.w);
    *(ushort4v*)(tile + (size_t)(((q >> 1) * 64 + rowl) * 8 + (q & 1) * 4)) = o;
  }
  __syncthreads();
  {
    const int rowl = t >> 2;                    // quad per row
    const int k = t & 3;
    float ss = 0.f;
#pragma unroll
    for (int j = 0; j < 8; ++j) ss += redy[rowl * 33 + k * 8 + j];
    DPPADD(ss, 0xB1);                           // quad xor1
    DPPADD(ss, 0x4E);                           // quad xor2 -> quad sum
    const int rowg = s * 64 + rowl;
    if ((t & 3) == 0) ny2[(size_t)s * 64 + rowl] = (rowg < M_B) ? (-0.5f * ss) : NEGF;
  }
#pragma unroll
  for (int i = 0; i < 4; ++i) {                 // coalesced 16B/lane global writes
    const int u = i * 256 + t;
    *(ushort8v*)(ybf + ((size_t)s * 1024 + u) * 8) = *(const ushort8v*)(tile + u * 8);
  }
}

// ---------------------------------------------------------------------------
// Main. R18: m201-GEOMETRY PORT. R9 post-mortem: nine schedule variants all
// land at 50+-3us / MfmaUtil ~41% because every config had 4-wave blocks =
// ONE wave per block per SIMD -- the geometry where within-wave scheduling
// tweaks are null (m131/m133/m137) and 8-phase never reproduced (m232).
// m201's 62%-MfmaUtil regime needs 2 SAME-BLOCK waves per SIMD + per-phase
// barriers + lgkmcnt(0)/sched_barrier before the MFMA cluster + setprio +
// once-per-tile counted vmcnt. Port:
//  - 512-thread blocks (8 waves, 2/SIMD), grid 256 = 1 block/CU
//    (CHUNKS=64, SPC=25, ROWBLOCKS=4); launch_bounds(512,2) -> 256 VGPR/wave
//    budget, no spill risk (R14/R15 lesson).
//  - rt=4 x 16x16x32 bf16, ct-OUTER: per slab 4 PHASES (one ct each), each
//    {4 ds_read_b128 (+phase0: 2 stage gloads) -> s_barrier -> lgkmcnt(0)
//     + sched_barrier(0) -> setprio(1) 16 MFMA setprio(0) -> fmax
//     -> [phase3: vmcnt(2|0)] -> s_barrier}.
//  - Triple-buffered LDS (3x16KB): stage slab s+2 at phase0 into the buffer
//    slab s-1 used (freed by preceding closing barrier); vmcnt counted ONCE
//    per slab at phase3 (2 = keep slab s+2's 2 loads in flight), never
//    drained mid-stream (T4).
// XCD: chunk = bid%64, 64%8==0 -> 4 rowblocks/chunk on one XCD (8 chunks x
// 4 = 32 blocks = the XCD's 32 CUs); chunk working set 416KB, L2-resident.
// MFMA layouts (verified m89/m91): A[m=lane&15][k=(lane>>4)*8+j],
// B[n=lane&15][k=(lane>>4)*8+j], C/D col=lane&15 row=(lane>>4)*4+reg.
// ---------------------------------------------------------------------------
__global__ __launch_bounds__(512, 2) void k_main(const float* __restrict__ X,
                                                 const unsigned short* __restrict__ ybf,
                                                 const float* __restrict__ ny2,
                                                 float* __restrict__ rsm) {
  __shared__ __align__(16) char smem[55552];
  unsigned short* ys = (unsigned short*)smem;        // 49152: three 16KB slab bufs
  float* ny2s = (float*)(smem + 49152);              //  6400: whole chunk's ny2 (25x64)

  const int bid = blockIdx.x;
  const int chunk = bid % CHUNKS;                    // 0..63 (XCD-local)
  const int rowblock = bid / CHUNKS;                 // 0..3
  const int row0 = rowblock * TROWS;

  const int cs0 = chunk * SPC;
  int nslab = SLABS_TOTAL - cs0;                     // chunk 62: 13; chunk 63: <=0
  if (nslab > SPC) nslab = SPC;
  if (nslab < 0) nslab = 0;

  const int t = threadIdx.x;                         // 0..511
  const int wave = t >> 6;                           // 0..7
  const int lane = t & 63;
  const int lm = lane & 15;
  const int lq = lane >> 4;                          // 0..3

  // ---- A fragments resident in registers (bf16): 64 rows per wave ----
  // afrag[rt][ks]: A[m=lm][k = lq*8 + j] for rowtile rt, k-step ks (K=32)
  short8 afrag[4][4];
#pragma unroll
  for (int rt = 0; rt < 4; ++rt)
#pragma unroll
    for (int ks = 0; ks < 4; ++ks) {
      const float* xr = X + (size_t)(row0 + wave * 64 + rt * 16 + lm) * D_DIM + ks * 32 + lq * 8;
      const float4 a = *(const float4*)xr;
      const float4 b = *(const float4*)(xr + 4);
      short8 f;
      f[0] = (short)f2bf(a.x); f[1] = (short)f2bf(a.y);
      f[2] = (short)f2bf(a.z); f[3] = (short)f2bf(a.w);
      f[4] = (short)f2bf(b.x); f[5] = (short)f2bf(b.y);
      f[6] = (short)f2bf(b.z); f[7] = (short)f2bf(b.w);
      afrag[rt][ks] = f;
    }

  // ---- one-time ny2 preload for the whole chunk (64 floats per slab) ----
  for (int j = wave; j < nslab; j += 8)
    gload_lds4(ny2 + (size_t)(cs0 + j) * 64 + lane, ny2s + (size_t)j * 64);

  // ---- prologue: stage slab 0 -> buf0, slab 1 -> buf1 (2 gloads each) ----
#pragma unroll
  for (int p = 0; p < 2; ++p) {
    if (p < nslab) {
      const unsigned short* src = ybf + (size_t)(cs0 + p) * 8192;
      unsigned short* dst = ys + (size_t)p * 8192;
#pragma unroll
      for (int i = 0; i < 2; ++i) {
        const int ub = i * 512 + t;                  // 1024 units of 16B
        gload_lds16(src + (size_t)ub * 8, dst + (size_t)ub * 8);
      }
    }
  }
  __syncthreads();   // full drain (vmcnt 0): afrag + ny2 + slabs 0,1 visible

  // persistent per-(row,class) running max: lane holds class lm, rows (rt,rr)
  float prmax[4][4];
#pragma unroll
  for (int rt = 0; rt < 4; ++rt)
#pragma unroll
    for (int rr = 0; rr < 4; ++rr) prmax[rt][rr] = NEGF;

  int cur = 0;                                       // buffer of slab s
  int stg = 2;                                       // buffer for slab s+2 (held s-1)
  for (int s = 0; s < nslab; ++s) {
    const unsigned short* yb = ys + (size_t)cur * 8192;
    const int do_stage = (s + 2 < nslab);

#pragma unroll
    for (int ct = 0; ct < 4; ++ct) {
      // ---- phase open: this ct's B-frag LDS reads + (phase0) staging ----
      const float yc = ny2s[s * 64 + ct * 16 + lm];  // -0.5*|y|^2, col ct*16+lm
      short8 bfr[4];
#pragma unroll
      for (int ks = 0; ks < 4; ++ks)
        bfr[ks] = *(const short8*)(yb + (size_t)(((ks * 4 + lq) * 64 + ct * 16 + lm)) * 8);

      if (ct == 0 && do_stage) {                     // issue-early (T14 shape)
        const unsigned short* src = ybf + (size_t)(cs0 + s + 2) * 8192;
        unsigned short* dst = ys + (size_t)stg * 8192;
#pragma unroll
        for (int i = 0; i < 2; ++i) {
          const int ub = i * 512 + t;
          gload_lds16(src + (size_t)ub * 8, dst + (size_t)ub * 8);
        }
      }

      __builtin_amdgcn_s_barrier();                  // phase-align the 8 waves
      asm volatile("s_waitcnt lgkmcnt(0)" ::: "memory");
      __builtin_amdgcn_sched_barrier(0);             // rule #18 fence

      f32x4 acc[4];                                  // [rowtile]
#pragma unroll
      for (int rt = 0; rt < 4; ++rt)
#pragma unroll
        for (int rr = 0; rr < 4; ++rr) acc[rt][rr] = yc;

      __builtin_amdgcn_s_setprio(1);
#pragma unroll
      for (int ks = 0; ks < 4; ++ks)
#pragma unroll
        for (int rt = 0; rt < 4; ++rt)
          acc[rt] = __builtin_amdgcn_mfma_f32_16x16x32_bf16(afrag[rt][ks], bfr[ks],
                                                            acc[rt], 0, 0, 0);
      __builtin_amdgcn_s_setprio(0);

#pragma unroll
      for (int rt = 0; rt < 4; ++rt)
#pragma unroll
        for (int rr = 0; rr < 4; ++rr)
          prmax[rt][rr] = fmaxf(prmax[rt][rr], acc[rt][rr]);

      if (ct == 3) {
        // gate slab s+1's DMA (oldest 2 loads) before its phase-0 ds_reads;
        // keep slab s+2's 2 loads in flight (T4: never drain mid-stream)
        if (do_stage) asm volatile("s_waitcnt vmcnt(2)" ::: "memory");
        else          asm volatile("s_waitcnt vmcnt(0)" ::: "memory");
      }
      __builtin_amdgcn_s_barrier();                  // phase close
    }

    // rotate: cur advances; freed buffer becomes the next stage target
    stg = cur;
    cur = (cur == 2) ? 0 : (cur + 1);
  }

  // ---- rsm write, row-major: rsm[row][chunk*CLS + lm], all 64 lanes ----
#pragma unroll
  for (int rt = 0; rt < 4; ++rt)
#pragma unroll
    for (int rr = 0; rr < 4; ++rr) {
      const int lrow = wave * 64 + rt * 16 + lq * 4 + rr;
      rsm[(size_t)(row0 + lrow) * FTOT + chunk * CLS + lm] = prmax[rt][rr];
    }
}

// ---------------------------------------------------------------------------
// K_scan: one wave per row. x2 = |x_row|^2 (fp32, wave reduce); top-5 largest
// acc over the row's 1024 class maxima (coalesced), per-lane sorted-5 + 5-round
// wave-max merge; d2 = x2 - 2*acc; sqrt/mean/normalize -> out[row].
// ---------------------------------------------------------------------------
__global__ __launch_bounds__(256) void k_scan(const float* __restrict__ rsm,
                                              const float* __restrict__ X,
                                              const float* __restrict__ minp,
                                              const float* __restrict__ maxp,
                                              float* __restrict__ out) {
  const int wave = threadIdx.x >> 6;
  const int lane = threadIdx.x & 63;
  const int row = blockIdx.x * 4 + wave;
  const float* rp = rsm + (size_t)row * FTOT;

  // x2: 2 floats per lane, butterfly sum
  float x2;
  {
    const float a = X[(size_t)row * D_DIM + lane];
    const float b = X[(size_t)row * D_DIM + 64 + lane];
    x2 = a * a + b * b;
#pragma unroll
    for (int off = 1; off < 64; off <<= 1) x2 += __shfl_xor(x2, off);
  }

  float t0 = NEGF, t1 = NEGF, t2 = NEGF, t3 = NEGF, t4 = NEGF;  // descending
  for (int i = lane; i < FTOT; i += 64) {
    const float v = rp[i];
    if (v > t4) {
      float m = v;
      float n3 = fminf(t3, m); m = fmaxf(t3, m);
      float n2 = fminf(t2, m); m = fmaxf(t2, m);
      float n1 = fminf(t1, m); m = fmaxf(t1, m);
      float n0 = fminf(t0, m); m = fmaxf(t0, m);
      t0 = m; t1 = n0; t2 = n1; t3 = n2; t4 = n3;
    }
  }

  int k = 0;
  float sum = 0.f;
#pragma unroll
  for (int r = 0; r < KNN; ++r) {
    float head = (k == 0) ? t0 : (k == 1) ? t1 : (k == 2) ? t2 : (k == 3) ? t3
               : (k == 4) ? t4 : NEGF;
    float m = head;
#pragma unroll
    for (int off = 1; off < 64; off <<= 1) m = fmaxf(m, __shfl_xor(m, off));
    const unsigned long long mask = __ballot(head == m);
    const int first = __ffsll(mask) - 1;
    if (lane == first) ++k;                      // consume exactly one holder
    sum += sqrtf(fmaxf(x2 - 2.f * m, 0.f));      // d = sqrt(x2 - 2*acc)
  }
  if (lane == 0) {
    const float mn = minp[0], mx = maxp[0];
    out[row] = (sum * (1.0f / KNN) - mn) / (mx - mn);
  }
}

extern "C" void kernel_launch(void* const* d_in, const int* in_sizes, int n_in,
                              void* d_out, int out_size, void* d_ws, size_t ws_size,
                              hipStream_t stream) {
  const float* X = (const float*)d_in[0];
  const float* Y = (const float*)d_in[1];
  const float* minp = (const float*)d_in[2];
  const float* maxp = (const float*)d_in[3];
  float* out = (float*)d_out;

  char* ws = (char*)d_ws;
  size_t off = 0;
  unsigned short* ybf = (unsigned short*)(ws + off); off += (size_t)M_PAD * D_DIM * 2;  // 25.6 MB
  float* ny2 = (float*)(ws + off);                   off += (size_t)M_PAD * 4;          // 400 KB
  float* rsm = (float*)(ws + off);                   off += (size_t)N_Q * FTOT * 4;     // 8.4 MB
  // total ~34.4 MB

  k_prep<<<dim3(SLABS_TOTAL), dim3(256), 0, stream>>>(Y, ybf, ny2);
  k_main<<<dim3(ROWBLOCKS * CHUNKS), dim3(512), 0, stream>>>(X, ybf, ny2, rsm);
  k_scan<<<dim3(N_Q / 4), dim3(256), 0, stream>>>(rsm, X, minp, maxp, out);
}